// Round 1
// baseline (1191.365 us; speedup 1.0000x reference)
//
#include <hip/hip_runtime.h>

#define N_NODES 50000
#define N_EDGES 800000
#define D 64
#define NUM_GRAPHS 512
#define FINAL_NEURON 128

// ---------------- degree / dinv ----------------
__global__ void k_init_deg(float* deg) {
    int i = blockIdx.x * blockDim.x + threadIdx.x;
    if (i < N_NODES) deg[i] = 1.0f;   // self-loop
}

__global__ void k_deg_count(const int* __restrict__ dst, float* deg) {
    int e = blockIdx.x * blockDim.x + threadIdx.x;
    if (e < N_EDGES) atomicAdd(&deg[dst[e]], 1.0f);
}

__global__ void k_dinv(float* deg) {
    int i = blockIdx.x * blockDim.x + threadIdx.x;
    if (i < N_NODES) deg[i] = rsqrtf(deg[i]);
}

// ---------------- per-layer GEMM: hw = h @ W ; agg = dinv^2 * hw ----------------
// block: 256 threads = 4 rows x 64 cols. W (64x64) staged in LDS.
__global__ void k_gemm(const float* __restrict__ h, const float* __restrict__ W,
                       const float* __restrict__ dinv,
                       float* __restrict__ hw, float* __restrict__ agg) {
    __shared__ float Ws[D * D];
    __shared__ float hs[4 * D];
    int t = threadIdx.x;
    int r = t >> 6;          // row within block, 0..3
    int j = t & 63;          // output column
    int row = blockIdx.x * 4 + r;

    #pragma unroll
    for (int i = t; i < D * D; i += 256) Ws[i] = W[i];
    if (row < N_NODES) hs[t] = h[row * D + j];
    __syncthreads();

    if (row >= N_NODES) return;
    float acc = 0.f;
    #pragma unroll
    for (int k = 0; k < D; ++k) acc += hs[r * D + k] * Ws[k * D + j];
    hw[row * D + j] = acc;
    float di = dinv[row];
    agg[row * D + j] = di * di * acc;   // self-loop contribution
}

// ---------------- edge scatter: agg[dst] += hw[src] * dinv[src]*dinv[dst] ----------------
// one wave (64 lanes) per edge; lane = feature.
__global__ void k_scatter(const int* __restrict__ src, const int* __restrict__ dst,
                          const float* __restrict__ dinv, const float* __restrict__ hw,
                          float* __restrict__ agg) {
    int tid = blockIdx.x * blockDim.x + threadIdx.x;
    int e = tid >> 6;
    int f = tid & 63;
    if (e >= N_EDGES) return;
    int s = src[e], d = dst[e];
    float norm = dinv[s] * dinv[d];
    atomicAdd(&agg[d * D + f], hw[s * D + f] * norm);
}

// ---------------- bias + relu ----------------
__global__ void k_bias_relu(const float* __restrict__ agg, const float* __restrict__ b,
                            float* __restrict__ h) {
    int tid = blockIdx.x * blockDim.x + threadIdx.x;
    if (tid >= N_NODES * D) return;
    float v = agg[tid] + b[tid & 63];
    h[tid] = v > 0.f ? v : 0.f;
}

// ---------------- pooling ----------------
__global__ void k_zero_g(float* g) {
    int i = blockIdx.x * blockDim.x + threadIdx.x;
    if (i < NUM_GRAPHS * D) g[i] = 0.f;
}

__global__ void k_pool(const int* __restrict__ batch, const float* __restrict__ h,
                       float* g) {
    int tid = blockIdx.x * blockDim.x + threadIdx.x;
    if (tid >= N_NODES * D) return;
    int i = tid >> 6, f = tid & 63;
    atomicAdd(&g[batch[i] * D + f], h[tid]);
}

// ---------------- fc1: g2 = relu(g @ fc1_W + fc1_b), 512x64 @ 64x128 ----------------
__global__ void k_fc1(const float* __restrict__ g, const float* __restrict__ W,
                      const float* __restrict__ b, float* __restrict__ g2) {
    int row = blockIdx.x;       // 512
    int j = threadIdx.x;        // 128
    float acc = 0.f;
    #pragma unroll
    for (int k = 0; k < D; ++k) acc += g[row * D + k] * W[k * FINAL_NEURON + j];
    acc += b[j];
    g2[row * FINAL_NEURON + j] = acc > 0.f ? acc : 0.f;
}

// ---------------- fc2: out = g2 @ fc2_W + fc2_b, 512x128 @ 128x1 ----------------
__global__ void k_fc2(const float* __restrict__ g2, const float* __restrict__ W,
                      const float* __restrict__ b, float* __restrict__ out) {
    int row = blockIdx.x * blockDim.x + threadIdx.x;
    if (row >= NUM_GRAPHS) return;
    float acc = b[0];
    #pragma unroll
    for (int k = 0; k < FINAL_NEURON; ++k) acc += g2[row * FINAL_NEURON + k] * W[k];
    out[row] = acc;
}

extern "C" void kernel_launch(void* const* d_in, const int* in_sizes, int n_in,
                              void* d_out, int out_size, void* d_ws, size_t ws_size,
                              hipStream_t stream) {
    const float* x     = (const float*)d_in[0];
    const int*   ei    = (const int*)d_in[1];
    const int*   src   = ei;
    const int*   dst   = ei + N_EDGES;
    const int*   batch = (const int*)d_in[2];
    const float* W[5]  = {(const float*)d_in[3], (const float*)d_in[5], (const float*)d_in[7],
                          (const float*)d_in[9], (const float*)d_in[11]};
    const float* b[5]  = {(const float*)d_in[4], (const float*)d_in[6], (const float*)d_in[8],
                          (const float*)d_in[10], (const float*)d_in[12]};
    const float* fc1W  = (const float*)d_in[13];
    const float* fc1b  = (const float*)d_in[14];
    const float* fc2W  = (const float*)d_in[15];
    const float* fc2b  = (const float*)d_in[16];
    float* out = (float*)d_out;

    float* dinv = (float*)d_ws;                  // N
    float* hbuf = dinv + N_NODES;                // N*D
    float* hw   = hbuf + (size_t)N_NODES * D;    // N*D
    float* agg  = hw   + (size_t)N_NODES * D;    // N*D
    float* g    = agg  + (size_t)N_NODES * D;    // G*D
    float* g2   = g    + NUM_GRAPHS * D;         // G*128

    // degree -> dinv
    k_init_deg <<<(N_NODES + 255) / 256, 256, 0, stream>>>(dinv);
    k_deg_count<<<(N_EDGES + 255) / 256, 256, 0, stream>>>(dst, dinv);
    k_dinv     <<<(N_NODES + 255) / 256, 256, 0, stream>>>(dinv);

    const float* hin = x;
    for (int L = 0; L < 5; ++L) {
        k_gemm<<<(N_NODES + 3) / 4, 256, 0, stream>>>(hin, W[L], dinv, hw, agg);
        k_scatter<<<(N_EDGES * 64) / 256, 256, 0, stream>>>(src, dst, dinv, hw, agg);
        k_bias_relu<<<(N_NODES * D + 255) / 256, 256, 0, stream>>>(agg, b[L], hbuf);
        hin = hbuf;
    }

    // readout + MLP
    k_zero_g<<<(NUM_GRAPHS * D + 255) / 256, 256, 0, stream>>>(g);
    k_pool<<<(N_NODES * D + 255) / 256, 256, 0, stream>>>(batch, hbuf, g);
    k_fc1<<<NUM_GRAPHS, FINAL_NEURON, 0, stream>>>(g, fc1W, fc1b, g2);
    k_fc2<<<(NUM_GRAPHS + 255) / 256, 256, 0, stream>>>(g2, fc2W, fc2b, out);
}

// Round 2
// 702.188 us; speedup vs baseline: 1.6966x; 1.6966x over previous
//
#include <hip/hip_runtime.h>

#define N_NODES 50000
#define N_EDGES 800000
#define D 64
#define NUM_GRAPHS 512
#define FINAL_NEURON 128

// ---------------- CSR build ----------------
__global__ void k_zero_int(int* p, int n) {
    int i = blockIdx.x * blockDim.x + threadIdx.x;
    if (i < n) p[i] = 0;
}

__global__ void k_hist(const int* __restrict__ dst, int* cnt) {
    int e = blockIdx.x * blockDim.x + threadIdx.x;
    if (e < N_EDGES) atomicAdd(&cnt[dst[e]], 1);
}

__global__ void k_dinv(const int* __restrict__ cnt, float* dinv) {
    int i = blockIdx.x * blockDim.x + threadIdx.x;
    if (i < N_NODES) dinv[i] = rsqrtf((float)cnt[i] + 1.0f);
}

// single-block exclusive scan over cnt[N] -> row[N+1]
__global__ void k_scan(const int* __restrict__ cnt, int* __restrict__ row) {
    __shared__ int buf[1024];
    __shared__ int carry_s;
    int t = threadIdx.x;
    if (t == 0) carry_s = 0;
    __syncthreads();
    for (int base = 0; base < N_NODES; base += 1024) {
        int i = base + t;
        int v = (i < N_NODES) ? cnt[i] : 0;
        buf[t] = v;
        __syncthreads();
        for (int off = 1; off < 1024; off <<= 1) {
            int add = (t >= off) ? buf[t - off] : 0;
            __syncthreads();
            buf[t] += add;
            __syncthreads();
        }
        int incl = buf[t];
        int carry = carry_s;
        if (i < N_NODES) row[i] = carry + incl - v;   // exclusive
        __syncthreads();
        if (t == 1023) carry_s = carry + incl;
        __syncthreads();
    }
    if (t == 0) row[N_NODES] = N_EDGES;
}

// place each edge into its CSR slot; precompute per-edge norm
__global__ void k_fill(const int* __restrict__ src, const int* __restrict__ dst,
                       const int* __restrict__ row, int* cur,
                       const float* __restrict__ dinv,
                       int* __restrict__ esrc, float* __restrict__ enorm) {
    int e = blockIdx.x * blockDim.x + threadIdx.x;
    if (e >= N_EDGES) return;
    int s = src[e], d = dst[e];
    int pos = atomicAdd(&cur[d], 1);
    int idx = row[d] + pos;
    esrc[idx] = s;
    enorm[idx] = dinv[s] * dinv[d];
}

// ---------------- per-layer GEMM: hw = h @ W ----------------
// block: 256 threads = 4 rows x 64 cols. W (64x64) staged in LDS.
__global__ void k_gemm(const float* __restrict__ h, const float* __restrict__ W,
                       float* __restrict__ hw) {
    __shared__ float Ws[D * D];
    __shared__ float hs[4 * D];
    int t = threadIdx.x;
    int r = t >> 6;
    int j = t & 63;
    int row = blockIdx.x * 4 + r;

    #pragma unroll
    for (int i = t; i < D * D; i += 256) Ws[i] = W[i];
    if (row < N_NODES) hs[t] = h[row * D + j];
    __syncthreads();

    if (row >= N_NODES) return;
    float acc = 0.f;
    #pragma unroll
    for (int k = 0; k < D; ++k) acc += hs[r * D + k] * Ws[k * D + j];
    hw[row * D + j] = acc;
}

// ---------------- CSR aggregate + self-loop + bias + relu ----------------
// block: 256 threads = 4 nodes x 64 features (lane = feature)
__global__ void k_aggregate(const int* __restrict__ row, const int* __restrict__ esrc,
                            const float* __restrict__ enorm, const float* __restrict__ hw,
                            const float* __restrict__ dinv, const float* __restrict__ b,
                            float* __restrict__ hout) {
    int t = threadIdx.x;
    int r = t >> 6;
    int f = t & 63;
    int n = blockIdx.x * 4 + r;
    if (n >= N_NODES) return;

    float di = dinv[n];
    float acc = di * di * hw[n * D + f];   // self-loop term

    int e = row[n], e1 = row[n + 1];
    for (; e + 1 < e1; e += 2) {
        int sA = esrc[e], sB = esrc[e + 1];
        float nA = enorm[e], nB = enorm[e + 1];
        float vA = hw[sA * D + f];
        float vB = hw[sB * D + f];
        acc += vA * nA + vB * nB;
    }
    if (e < e1) acc += hw[esrc[e] * D + f] * enorm[e];

    acc += b[f];
    hout[n * D + f] = acc > 0.f ? acc : 0.f;
}

// ---------------- pooling ----------------
__global__ void k_zero_g(float* g) {
    int i = blockIdx.x * blockDim.x + threadIdx.x;
    if (i < NUM_GRAPHS * D) g[i] = 0.f;
}

__global__ void k_pool(const int* __restrict__ batch, const float* __restrict__ h,
                       float* g) {
    int tid = blockIdx.x * blockDim.x + threadIdx.x;
    if (tid >= N_NODES * D) return;
    int i = tid >> 6, f = tid & 63;
    atomicAdd(&g[batch[i] * D + f], h[tid]);
}

// ---------------- fc1 ----------------
__global__ void k_fc1(const float* __restrict__ g, const float* __restrict__ W,
                      const float* __restrict__ b, float* __restrict__ g2) {
    int row = blockIdx.x;
    int j = threadIdx.x;
    float acc = 0.f;
    #pragma unroll
    for (int k = 0; k < D; ++k) acc += g[row * D + k] * W[k * FINAL_NEURON + j];
    acc += b[j];
    g2[row * FINAL_NEURON + j] = acc > 0.f ? acc : 0.f;
}

// ---------------- fc2 ----------------
__global__ void k_fc2(const float* __restrict__ g2, const float* __restrict__ W,
                      const float* __restrict__ b, float* __restrict__ out) {
    int row = blockIdx.x * blockDim.x + threadIdx.x;
    if (row >= NUM_GRAPHS) return;
    float acc = b[0];
    #pragma unroll
    for (int k = 0; k < FINAL_NEURON; ++k) acc += g2[row * FINAL_NEURON + k] * W[k];
    out[row] = acc;
}

extern "C" void kernel_launch(void* const* d_in, const int* in_sizes, int n_in,
                              void* d_out, int out_size, void* d_ws, size_t ws_size,
                              hipStream_t stream) {
    const float* x     = (const float*)d_in[0];
    const int*   ei    = (const int*)d_in[1];
    const int*   src   = ei;
    const int*   dst   = ei + N_EDGES;
    const int*   batch = (const int*)d_in[2];
    const float* W[5]  = {(const float*)d_in[3], (const float*)d_in[5], (const float*)d_in[7],
                          (const float*)d_in[9], (const float*)d_in[11]};
    const float* b[5]  = {(const float*)d_in[4], (const float*)d_in[6], (const float*)d_in[8],
                          (const float*)d_in[10], (const float*)d_in[12]};
    const float* fc1W  = (const float*)d_in[13];
    const float* fc1b  = (const float*)d_in[14];
    const float* fc2W  = (const float*)d_in[15];
    const float* fc2b  = (const float*)d_in[16];
    float* out = (float*)d_out;

    float* dinv  = (float*)d_ws;                    // N
    int*   cnt   = (int*)(dinv + N_NODES);          // N
    int*   row   = cnt + N_NODES;                   // N+1
    int*   cur   = row + N_NODES + 1;               // N
    int*   esrc  = cur + N_NODES;                   // E
    float* enorm = (float*)(esrc + N_EDGES);        // E
    float* hbuf  = enorm + N_EDGES;                 // N*D
    float* hw    = hbuf + (size_t)N_NODES * D;      // N*D
    float* g     = hw + (size_t)N_NODES * D;        // G*D
    float* g2    = g + NUM_GRAPHS * D;              // G*128

    // ---- CSR build (once per call, reused by all 5 layers) ----
    k_zero_int<<<(N_NODES + 255) / 256, 256, 0, stream>>>(cnt, N_NODES);
    k_zero_int<<<(N_NODES + 255) / 256, 256, 0, stream>>>(cur, N_NODES);
    k_hist<<<(N_EDGES + 255) / 256, 256, 0, stream>>>(dst, cnt);
    k_dinv<<<(N_NODES + 255) / 256, 256, 0, stream>>>(cnt, dinv);
    k_scan<<<1, 1024, 0, stream>>>(cnt, row);
    k_fill<<<(N_EDGES + 255) / 256, 256, 0, stream>>>(src, dst, row, cur, dinv, esrc, enorm);

    // ---- 5 GCN layers ----
    const float* hin = x;
    for (int L = 0; L < 5; ++L) {
        k_gemm<<<(N_NODES + 3) / 4, 256, 0, stream>>>(hin, W[L], hw);
        k_aggregate<<<(N_NODES + 3) / 4, 256, 0, stream>>>(row, esrc, enorm, hw, dinv, b[L], hbuf);
        hin = hbuf;
    }

    // ---- readout + MLP ----
    k_zero_g<<<(NUM_GRAPHS * D + 255) / 256, 256, 0, stream>>>(g);
    k_pool<<<(N_NODES * D + 255) / 256, 256, 0, stream>>>(batch, hbuf, g);
    k_fc1<<<NUM_GRAPHS, FINAL_NEURON, 0, stream>>>(g, fc1W, fc1b, g2);
    k_fc2<<<(NUM_GRAPHS + 255) / 256, 256, 0, stream>>>(g2, fc2W, fc2b, out);
}

// Round 3
// 476.892 us; speedup vs baseline: 2.4982x; 1.4724x over previous
//
#include <hip/hip_runtime.h>

#define N_NODES 50000
#define N_EDGES 800000
#define D 64
#define NUM_GRAPHS 512
#define FINAL_NEURON 128
#define SCAN_NB ((N_NODES + 255) / 256)   // 196 blocks

// ---------------- CSR build ----------------
__global__ void k_zero_int(int* p, int n) {
    int i = blockIdx.x * blockDim.x + threadIdx.x;
    if (i < n) p[i] = 0;
}

__global__ void k_hist(const int* __restrict__ dst, int* cnt) {
    int e = blockIdx.x * blockDim.x + threadIdx.x;
    if (e < N_EDGES) atomicAdd(&cnt[dst[e]], 1);
}

__global__ void k_dinv(const int* __restrict__ cnt, float* dinv) {
    int i = blockIdx.x * blockDim.x + threadIdx.x;
    if (i < N_NODES) dinv[i] = rsqrtf((float)cnt[i] + 1.0f);
}

// phase A: per-block sums of cnt
__global__ void k_blocksum(const int* __restrict__ cnt, int* __restrict__ bsum) {
    __shared__ int sdata[256];
    int t = threadIdx.x;
    int i = blockIdx.x * 256 + t;
    sdata[t] = (i < N_NODES) ? cnt[i] : 0;
    __syncthreads();
    for (int s = 128; s > 0; s >>= 1) {
        if (t < s) sdata[t] += sdata[t + s];
        __syncthreads();
    }
    if (t == 0) bsum[blockIdx.x] = sdata[0];
}

// phase B: single-block exclusive scan of 196 block sums
__global__ void k_scanbsum(const int* __restrict__ bsum, int* __restrict__ boff) {
    __shared__ int buf[256];
    int t = threadIdx.x;
    int v = (t < SCAN_NB) ? bsum[t] : 0;
    buf[t] = v;
    __syncthreads();
    for (int off = 1; off < 256; off <<= 1) {
        int a = (t >= off) ? buf[t - off] : 0;
        __syncthreads();
        buf[t] += a;
        __syncthreads();
    }
    if (t < SCAN_NB) boff[t] = buf[t] - v;   // exclusive
}

// phase C: local exclusive scan + block offset -> row
__global__ void k_localscan(const int* __restrict__ cnt, const int* __restrict__ boff,
                            int* __restrict__ row) {
    __shared__ int buf[256];
    int t = threadIdx.x;
    int i = blockIdx.x * 256 + t;
    int v = (i < N_NODES) ? cnt[i] : 0;
    buf[t] = v;
    __syncthreads();
    for (int off = 1; off < 256; off <<= 1) {
        int a = (t >= off) ? buf[t - off] : 0;
        __syncthreads();
        buf[t] += a;
        __syncthreads();
    }
    if (i < N_NODES) row[i] = boff[blockIdx.x] + buf[t] - v;
    if (i == 0) row[N_NODES] = N_EDGES;
}

__global__ void k_fill(const int* __restrict__ src, const int* __restrict__ dst,
                       const int* __restrict__ row, int* cur,
                       const float* __restrict__ dinv,
                       int* __restrict__ esrc, float* __restrict__ enorm) {
    int e = blockIdx.x * blockDim.x + threadIdx.x;
    if (e >= N_EDGES) return;
    int s = src[e], d = dst[e];
    int pos = atomicAdd(&cur[d], 1);
    int idx = row[d] + pos;
    esrc[idx] = s;
    enorm[idx] = dinv[s] * dinv[d];
}

// ---------------- per-layer GEMM: hw = h @ W ----------------
// 256 threads = 16 rows x 16 col-groups; each thread computes float4 (4 cols).
__global__ void k_gemm(const float* __restrict__ h, const float* __restrict__ W,
                       float* __restrict__ hw) {
    __shared__ float4 Ws4[D * 16];       // W[k][j4], 16 KB
    __shared__ float  hs[16 * 68];       // 16 rows, stride 68 (bank-conflict-free, 16B aligned)
    int t = threadIdx.x;
    int r = t >> 4;          // row in tile 0..15
    int c = t & 15;          // float4 col group 0..15
    int base = blockIdx.x * 16;
    int n = base + r;

    const float4* W4 = (const float4*)W;
    #pragma unroll
    for (int idx = t; idx < D * 16; idx += 256) Ws4[idx] = W4[idx];
    if (n < N_NODES) {
        float4 hv = ((const float4*)h)[(size_t)n * 16 + c];
        *(float4*)&hs[r * 68 + c * 4] = hv;
    }
    __syncthreads();

    if (n >= N_NODES) return;
    float4 acc = {0.f, 0.f, 0.f, 0.f};
    #pragma unroll
    for (int k = 0; k < D; ++k) {
        float a = hs[r * 68 + k];
        float4 w = Ws4[k * 16 + c];
        acc.x += a * w.x; acc.y += a * w.y; acc.z += a * w.z; acc.w += a * w.w;
    }
    ((float4*)hw)[(size_t)n * 16 + c] = acc;
}

// ---------------- CSR aggregate + self-loop + bias + relu ----------------
// 256 threads = 4 waves; wave = 1 node; lanes = 4 edge-subgroups x 16 float4-cols.
__global__ void k_aggregate(const int* __restrict__ row, const int* __restrict__ esrc,
                            const float* __restrict__ enorm, const float* __restrict__ hw,
                            const float* __restrict__ dinv, const float* __restrict__ b,
                            float* __restrict__ hout) {
    int t = threadIdx.x;
    int w = t >> 6;
    int l = t & 63;
    int n = blockIdx.x * 4 + w;
    if (n >= N_NODES) return;
    int sub = l >> 4;        // 0..3: which edge in the group of 4
    int c = l & 15;          // float4 column group

    const float4* hw4 = (const float4*)hw;
    float4 acc = {0.f, 0.f, 0.f, 0.f};
    int e1 = row[n + 1];
    for (int e = row[n] + sub; e < e1; e += 4) {
        int s = esrc[e];
        float nm = enorm[e];
        float4 v = hw4[(size_t)s * 16 + c];
        acc.x += v.x * nm; acc.y += v.y * nm; acc.z += v.z * nm; acc.w += v.w * nm;
    }
    if (sub == 0) {          // self-loop, added exactly once
        float di = dinv[n];
        float sc = di * di;
        float4 v = hw4[(size_t)n * 16 + c];
        acc.x += v.x * sc; acc.y += v.y * sc; acc.z += v.z * sc; acc.w += v.w * sc;
    }
    // reduce across the 4 subgroups (lanes l, l^16, l^32, l^48)
    acc.x += __shfl_xor(acc.x, 16); acc.y += __shfl_xor(acc.y, 16);
    acc.z += __shfl_xor(acc.z, 16); acc.w += __shfl_xor(acc.w, 16);
    acc.x += __shfl_xor(acc.x, 32); acc.y += __shfl_xor(acc.y, 32);
    acc.z += __shfl_xor(acc.z, 32); acc.w += __shfl_xor(acc.w, 32);

    if (sub == 0) {
        float4 bb = ((const float4*)b)[c];
        float4 r;
        r.x = fmaxf(acc.x + bb.x, 0.f);
        r.y = fmaxf(acc.y + bb.y, 0.f);
        r.z = fmaxf(acc.z + bb.z, 0.f);
        r.w = fmaxf(acc.w + bb.w, 0.f);
        ((float4*)hout)[(size_t)n * 16 + c] = r;
    }
}

// ---------------- pooling ----------------
__global__ void k_zero_g(float* g) {
    int i = blockIdx.x * blockDim.x + threadIdx.x;
    if (i < NUM_GRAPHS * D) g[i] = 0.f;
}

// 8 nodes per thread-column; flush atomic only when graph id changes
__global__ void k_pool(const int* __restrict__ batch, const float* __restrict__ h,
                       float* g) {
    int tid = blockIdx.x * blockDim.x + threadIdx.x;
    int f = tid & 63;
    int n0 = (tid >> 6) * 8;
    if (n0 >= N_NODES) return;
    int n1 = n0 + 8; if (n1 > N_NODES) n1 = N_NODES;
    int curb = batch[n0];
    float acc = 0.f;
    for (int n = n0; n < n1; ++n) {
        int bb = batch[n];
        if (bb != curb) { atomicAdd(&g[curb * D + f], acc); acc = 0.f; curb = bb; }
        acc += h[(size_t)n * D + f];
    }
    atomicAdd(&g[curb * D + f], acc);
}

// ---------------- fc1 ----------------
__global__ void k_fc1(const float* __restrict__ g, const float* __restrict__ W,
                      const float* __restrict__ b, float* __restrict__ g2) {
    int row = blockIdx.x;
    int j = threadIdx.x;
    float acc = 0.f;
    #pragma unroll
    for (int k = 0; k < D; ++k) acc += g[row * D + k] * W[k * FINAL_NEURON + j];
    acc += b[j];
    g2[row * FINAL_NEURON + j] = acc > 0.f ? acc : 0.f;
}

// ---------------- fc2 ----------------
__global__ void k_fc2(const float* __restrict__ g2, const float* __restrict__ W,
                      const float* __restrict__ b, float* __restrict__ out) {
    int row = blockIdx.x * blockDim.x + threadIdx.x;
    if (row >= NUM_GRAPHS) return;
    float acc = b[0];
    #pragma unroll
    for (int k = 0; k < FINAL_NEURON; ++k) acc += g2[row * FINAL_NEURON + k] * W[k];
    out[row] = acc;
}

extern "C" void kernel_launch(void* const* d_in, const int* in_sizes, int n_in,
                              void* d_out, int out_size, void* d_ws, size_t ws_size,
                              hipStream_t stream) {
    const float* x     = (const float*)d_in[0];
    const int*   ei    = (const int*)d_in[1];
    const int*   src   = ei;
    const int*   dst   = ei + N_EDGES;
    const int*   batch = (const int*)d_in[2];
    const float* W[5]  = {(const float*)d_in[3], (const float*)d_in[5], (const float*)d_in[7],
                          (const float*)d_in[9], (const float*)d_in[11]};
    const float* b[5]  = {(const float*)d_in[4], (const float*)d_in[6], (const float*)d_in[8],
                          (const float*)d_in[10], (const float*)d_in[12]};
    const float* fc1W  = (const float*)d_in[13];
    const float* fc1b  = (const float*)d_in[14];
    const float* fc2W  = (const float*)d_in[15];
    const float* fc2b  = (const float*)d_in[16];
    float* out = (float*)d_out;

    float* dinv  = (float*)d_ws;                    // N
    int*   cnt   = (int*)(dinv + N_NODES);          // N
    int*   row   = cnt + N_NODES;                   // N+1
    int*   cur   = row + N_NODES + 1;               // N
    int*   bsum  = cur + N_NODES;                   // 256
    int*   boff  = bsum + 256;                      // 256
    int*   esrc  = boff + 256;                      // E
    float* enorm = (float*)(esrc + N_EDGES);        // E
    float* hbuf  = enorm + N_EDGES;                 // N*D
    float* hw    = hbuf + (size_t)N_NODES * D;      // N*D
    float* g     = hw + (size_t)N_NODES * D;        // G*D
    float* g2    = g + NUM_GRAPHS * D;              // G*128

    // ---- CSR build ----
    k_zero_int<<<(N_NODES + 255) / 256, 256, 0, stream>>>(cnt, N_NODES);
    k_zero_int<<<(N_NODES + 255) / 256, 256, 0, stream>>>(cur, N_NODES);
    k_hist<<<(N_EDGES + 255) / 256, 256, 0, stream>>>(dst, cnt);
    k_dinv<<<(N_NODES + 255) / 256, 256, 0, stream>>>(cnt, dinv);
    k_blocksum<<<SCAN_NB, 256, 0, stream>>>(cnt, bsum);
    k_scanbsum<<<1, 256, 0, stream>>>(bsum, boff);
    k_localscan<<<SCAN_NB, 256, 0, stream>>>(cnt, boff, row);
    k_fill<<<(N_EDGES + 255) / 256, 256, 0, stream>>>(src, dst, row, cur, dinv, esrc, enorm);

    // ---- 5 GCN layers ----
    const float* hin = x;
    for (int L = 0; L < 5; ++L) {
        k_gemm<<<(N_NODES + 15) / 16, 256, 0, stream>>>(hin, W[L], hw);
        k_aggregate<<<(N_NODES + 3) / 4, 256, 0, stream>>>(row, esrc, enorm, hw, dinv, b[L], hbuf);
        hin = hbuf;
    }

    // ---- readout + MLP ----
    k_zero_g<<<(NUM_GRAPHS * D + 255) / 256, 256, 0, stream>>>(g);
    k_pool<<<((N_NODES + 7) / 8 * 64 + 255) / 256, 256, 0, stream>>>(batch, hbuf, g);
    k_fc1<<<NUM_GRAPHS, FINAL_NEURON, 0, stream>>>(g, fc1W, fc1b, g2);
    k_fc2<<<(NUM_GRAPHS + 255) / 256, 256, 0, stream>>>(g2, fc2W, fc2b, out);
}

// Round 4
// 462.376 us; speedup vs baseline: 2.5766x; 1.0314x over previous
//
#include <hip/hip_runtime.h>

#define N_NODES 50000
#define N_EDGES 800000
#define D 64
#define NUM_GRAPHS 512
#define FINAL_NEURON 128
#define SCAN_NB ((N_NODES + 255) / 256)   // 196 blocks

// ---------------- CSR build ----------------
__global__ void k_zero2(int* a, int* b, int n) {
    int i = blockIdx.x * blockDim.x + threadIdx.x;
    if (i < n) { a[i] = 0; b[i] = 0; }
}

__global__ void k_hist(const int* __restrict__ dst, int* cnt) {
    int e = blockIdx.x * blockDim.x + threadIdx.x;
    if (e < N_EDGES) atomicAdd(&cnt[dst[e]], 1);
}

// per-block sums of cnt; also emit dinv = rsqrt(cnt+1)
__global__ void k_blocksum(const int* __restrict__ cnt, int* __restrict__ bsum,
                           float* __restrict__ dinv) {
    __shared__ int sdata[256];
    int t = threadIdx.x;
    int i = blockIdx.x * 256 + t;
    int v = (i < N_NODES) ? cnt[i] : 0;
    if (i < N_NODES) dinv[i] = rsqrtf((float)v + 1.0f);
    sdata[t] = v;
    __syncthreads();
    for (int s = 128; s > 0; s >>= 1) {
        if (t < s) sdata[t] += sdata[t + s];
        __syncthreads();
    }
    if (t == 0) bsum[blockIdx.x] = sdata[0];
}

// single-block exclusive scan of block sums
__global__ void k_scanbsum(const int* __restrict__ bsum, int* __restrict__ boff) {
    __shared__ int buf[256];
    int t = threadIdx.x;
    int v = (t < SCAN_NB) ? bsum[t] : 0;
    buf[t] = v;
    __syncthreads();
    for (int off = 1; off < 256; off <<= 1) {
        int a = (t >= off) ? buf[t - off] : 0;
        __syncthreads();
        buf[t] += a;
        __syncthreads();
    }
    if (t < SCAN_NB) boff[t] = buf[t] - v;   // exclusive
}

// local exclusive scan + block offset -> row
__global__ void k_localscan(const int* __restrict__ cnt, const int* __restrict__ boff,
                            int* __restrict__ row) {
    __shared__ int buf[256];
    int t = threadIdx.x;
    int i = blockIdx.x * 256 + t;
    int v = (i < N_NODES) ? cnt[i] : 0;
    buf[t] = v;
    __syncthreads();
    for (int off = 1; off < 256; off <<= 1) {
        int a = (t >= off) ? buf[t - off] : 0;
        __syncthreads();
        buf[t] += a;
        __syncthreads();
    }
    if (i < N_NODES) row[i] = boff[blockIdx.x] + buf[t] - v;
    if (i == 0) row[N_NODES] = N_EDGES;
}

// place each edge: one packed 8B store {src, norm}
__global__ void k_fill(const int* __restrict__ src, const int* __restrict__ dst,
                       const int* __restrict__ row, int* cur,
                       const float* __restrict__ dinv,
                       int2* __restrict__ edge) {
    int e = blockIdx.x * blockDim.x + threadIdx.x;
    if (e >= N_EDGES) return;
    int s = src[e], d = dst[e];
    int pos = atomicAdd(&cur[d], 1);
    float nm = dinv[s] * dinv[d];
    int2 packed = {s, __float_as_int(nm)};
    edge[row[d] + pos] = packed;
}

// ---------------- per-layer GEMM: hw = h @ W ----------------
// 256 threads = 16 rows x 16 col-groups; each thread computes float4 (4 cols).
__global__ void k_gemm(const float* __restrict__ h, const float* __restrict__ W,
                       float* __restrict__ hw) {
    __shared__ float4 Ws4[D * 16];       // 16 KB
    __shared__ float  hs[16 * 68];       // padded rows, 16B-aligned (272B stride)
    int t = threadIdx.x;
    int r = t >> 4;
    int c = t & 15;
    int n = blockIdx.x * 16 + r;

    const float4* W4 = (const float4*)W;
    #pragma unroll
    for (int idx = t; idx < D * 16; idx += 256) Ws4[idx] = W4[idx];
    if (n < N_NODES) {
        float4 hv = ((const float4*)h)[(size_t)n * 16 + c];
        *(float4*)&hs[r * 68 + c * 4] = hv;
    }
    __syncthreads();

    if (n >= N_NODES) return;
    const float4* hrow = (const float4*)&hs[r * 68];
    float4 acc = {0.f, 0.f, 0.f, 0.f};
    #pragma unroll
    for (int kk = 0; kk < 16; ++kk) {
        float4 hv = hrow[kk];
        float4 w0 = Ws4[(kk * 4 + 0) * 16 + c];
        float4 w1 = Ws4[(kk * 4 + 1) * 16 + c];
        float4 w2 = Ws4[(kk * 4 + 2) * 16 + c];
        float4 w3 = Ws4[(kk * 4 + 3) * 16 + c];
        acc.x += hv.x * w0.x + hv.y * w1.x + hv.z * w2.x + hv.w * w3.x;
        acc.y += hv.x * w0.y + hv.y * w1.y + hv.z * w2.y + hv.w * w3.y;
        acc.z += hv.x * w0.z + hv.y * w1.z + hv.z * w2.z + hv.w * w3.z;
        acc.w += hv.x * w0.w + hv.y * w1.w + hv.z * w2.w + hv.w * w3.w;
    }
    ((float4*)hw)[(size_t)n * 16 + c] = acc;
}

// ---------------- CSR aggregate + self-loop + bias + relu ----------------
// 256 threads = 4 waves; wave = 1 node; 8 edge-subgroups x 8 lanes; each lane
// covers 2 float4 column-groups -> 16 outstanding loads per wave.
__global__ void k_aggregate(const int* __restrict__ row, const int2* __restrict__ edge,
                            const float* __restrict__ hw,
                            const float* __restrict__ dinv, const float* __restrict__ b,
                            float* __restrict__ hout) {
    int t = threadIdx.x;
    int w = t >> 6;
    int l = t & 63;
    int n = blockIdx.x * 4 + w;
    if (n >= N_NODES) return;
    int sub = l >> 3;        // 0..7: edge slot
    int c = l & 7;           // float4 col group (first half)

    const float4* hw4 = (const float4*)hw;
    float4 acc0 = {0.f, 0.f, 0.f, 0.f};
    float4 acc1 = {0.f, 0.f, 0.f, 0.f};
    int e0 = row[n], e1 = row[n + 1];
    for (int e = e0 + sub; e < e1; e += 8) {
        int2 ed = edge[e];
        int s = ed.x;
        float nm = __int_as_float(ed.y);
        float4 v0 = hw4[(size_t)s * 16 + c];
        float4 v1 = hw4[(size_t)s * 16 + c + 8];
        acc0.x += v0.x * nm; acc0.y += v0.y * nm; acc0.z += v0.z * nm; acc0.w += v0.w * nm;
        acc1.x += v1.x * nm; acc1.y += v1.y * nm; acc1.z += v1.z * nm; acc1.w += v1.w * nm;
    }
    if (sub == 0) {          // self-loop, exactly once
        float di = dinv[n];
        float sc = di * di;
        float4 v0 = hw4[(size_t)n * 16 + c];
        float4 v1 = hw4[(size_t)n * 16 + c + 8];
        acc0.x += v0.x * sc; acc0.y += v0.y * sc; acc0.z += v0.z * sc; acc0.w += v0.w * sc;
        acc1.x += v1.x * sc; acc1.y += v1.y * sc; acc1.z += v1.z * sc; acc1.w += v1.w * sc;
    }
    // reduce across the 8 subgroups (xor 8, 16, 32)
    #pragma unroll
    for (int m = 8; m < 64; m <<= 1) {
        acc0.x += __shfl_xor(acc0.x, m); acc0.y += __shfl_xor(acc0.y, m);
        acc0.z += __shfl_xor(acc0.z, m); acc0.w += __shfl_xor(acc0.w, m);
        acc1.x += __shfl_xor(acc1.x, m); acc1.y += __shfl_xor(acc1.y, m);
        acc1.z += __shfl_xor(acc1.z, m); acc1.w += __shfl_xor(acc1.w, m);
    }

    if (sub == 0) {
        float4 b0 = ((const float4*)b)[c];
        float4 b1 = ((const float4*)b)[c + 8];
        float4 r0, r1;
        r0.x = fmaxf(acc0.x + b0.x, 0.f); r0.y = fmaxf(acc0.y + b0.y, 0.f);
        r0.z = fmaxf(acc0.z + b0.z, 0.f); r0.w = fmaxf(acc0.w + b0.w, 0.f);
        r1.x = fmaxf(acc1.x + b1.x, 0.f); r1.y = fmaxf(acc1.y + b1.y, 0.f);
        r1.z = fmaxf(acc1.z + b1.z, 0.f); r1.w = fmaxf(acc1.w + b1.w, 0.f);
        ((float4*)hout)[(size_t)n * 16 + c] = r0;
        ((float4*)hout)[(size_t)n * 16 + c + 8] = r1;
    }
}

// ---------------- pooling ----------------
__global__ void k_zero_g(float* g) {
    int i = blockIdx.x * blockDim.x + threadIdx.x;
    if (i < NUM_GRAPHS * D) g[i] = 0.f;
}

__global__ void k_pool(const int* __restrict__ batch, const float* __restrict__ h,
                       float* g) {
    int tid = blockIdx.x * blockDim.x + threadIdx.x;
    int f = tid & 63;
    int n0 = (tid >> 6) * 8;
    if (n0 >= N_NODES) return;
    int n1 = n0 + 8; if (n1 > N_NODES) n1 = N_NODES;
    int curb = batch[n0];
    float acc = 0.f;
    for (int n = n0; n < n1; ++n) {
        int bb = batch[n];
        if (bb != curb) { atomicAdd(&g[curb * D + f], acc); acc = 0.f; curb = bb; }
        acc += h[(size_t)n * D + f];
    }
    atomicAdd(&g[curb * D + f], acc);
}

// ---------------- fc1 ----------------
__global__ void k_fc1(const float* __restrict__ g, const float* __restrict__ W,
                      const float* __restrict__ b, float* __restrict__ g2) {
    int row = blockIdx.x;
    int j = threadIdx.x;
    float acc = 0.f;
    #pragma unroll
    for (int k = 0; k < D; ++k) acc += g[row * D + k] * W[k * FINAL_NEURON + j];
    acc += b[j];
    g2[row * FINAL_NEURON + j] = acc > 0.f ? acc : 0.f;
}

// ---------------- fc2 ----------------
__global__ void k_fc2(const float* __restrict__ g2, const float* __restrict__ W,
                      const float* __restrict__ b, float* __restrict__ out) {
    int row = blockIdx.x * blockDim.x + threadIdx.x;
    if (row >= NUM_GRAPHS) return;
    float acc = b[0];
    #pragma unroll
    for (int k = 0; k < FINAL_NEURON; ++k) acc += g2[row * FINAL_NEURON + k] * W[k];
    out[row] = acc;
}

extern "C" void kernel_launch(void* const* d_in, const int* in_sizes, int n_in,
                              void* d_out, int out_size, void* d_ws, size_t ws_size,
                              hipStream_t stream) {
    const float* x     = (const float*)d_in[0];
    const int*   ei    = (const int*)d_in[1];
    const int*   src   = ei;
    const int*   dst   = ei + N_EDGES;
    const int*   batch = (const int*)d_in[2];
    const float* W[5]  = {(const float*)d_in[3], (const float*)d_in[5], (const float*)d_in[7],
                          (const float*)d_in[9], (const float*)d_in[11]};
    const float* b[5]  = {(const float*)d_in[4], (const float*)d_in[6], (const float*)d_in[8],
                          (const float*)d_in[10], (const float*)d_in[12]};
    const float* fc1W  = (const float*)d_in[13];
    const float* fc1b  = (const float*)d_in[14];
    const float* fc2W  = (const float*)d_in[15];
    const float* fc2b  = (const float*)d_in[16];
    float* out = (float*)d_out;

    // ws layout (edge first for 8B alignment)
    int2*  edge  = (int2*)d_ws;                     // E int2
    float* dinv  = (float*)(edge + N_EDGES);        // N
    int*   cnt   = (int*)(dinv + N_NODES);          // N
    int*   row   = cnt + N_NODES;                   // N+1
    int*   cur   = row + N_NODES + 1;               // N
    int*   bsum  = cur + N_NODES;                   // 256
    int*   boff  = bsum + 256;                      // 256
    float* hbuf  = (float*)(boff + 256);            // N*D
    float* hw    = hbuf + (size_t)N_NODES * D;      // N*D
    float* g     = hw + (size_t)N_NODES * D;        // G*D
    float* g2    = g + NUM_GRAPHS * D;              // G*128

    // ---- CSR build ----
    k_zero2<<<(N_NODES + 255) / 256, 256, 0, stream>>>(cnt, cur, N_NODES);
    k_hist<<<(N_EDGES + 255) / 256, 256, 0, stream>>>(dst, cnt);
    k_blocksum<<<SCAN_NB, 256, 0, stream>>>(cnt, bsum, dinv);
    k_scanbsum<<<1, 256, 0, stream>>>(bsum, boff);
    k_localscan<<<SCAN_NB, 256, 0, stream>>>(cnt, boff, row);
    k_fill<<<(N_EDGES + 255) / 256, 256, 0, stream>>>(src, dst, row, cur, dinv, edge);

    // ---- 5 GCN layers ----
    const float* hin = x;
    for (int L = 0; L < 5; ++L) {
        k_gemm<<<(N_NODES + 15) / 16, 256, 0, stream>>>(hin, W[L], hw);
        k_aggregate<<<(N_NODES + 3) / 4, 256, 0, stream>>>(row, edge, hw, dinv, b[L], hbuf);
        hin = hbuf;
    }

    // ---- readout + MLP ----
    k_zero_g<<<(NUM_GRAPHS * D + 255) / 256, 256, 0, stream>>>(g);
    k_pool<<<((N_NODES + 7) / 8 * 64 + 255) / 256, 256, 0, stream>>>(batch, hbuf, g);
    k_fc1<<<NUM_GRAPHS, FINAL_NEURON, 0, stream>>>(g, fc1W, fc1b, g2);
    k_fc2<<<(NUM_GRAPHS + 255) / 256, 256, 0, stream>>>(g2, fc2W, fc2b, out);
}